// Round 3
// baseline (67469.067 us; speedup 1.0000x reference)
//
#include <hip/hip_runtime.h>
#include <cmath>

// Problem constants
#define BB 64
#define LL 96
#define HH 1024
#define MM 512
#define LH 98304            // L*H
#define ATT0 6291456        // B*L*H  (start of attn outputs in d_out)

__device__ __forceinline__ float sigmoidf_(float x) { return 1.0f / (1.0f + expf(-x)); }

// ---------------------------------------------------------------------------
// Scalar-W GEMM (no LDS): lane = batch row (64 rows = 1 wave).
//   P[s][b][n] = sum_{k in split s} AT[k][b] * W[n][k]
// AT is the k-major transpose of the activation, as the virtual concat of
// A0T [KA0][64] and A1T [K-KA0][64]. W is row-major [N][ldw] selected between
// W0 (k < KW0) and W1 (k >= KW0). W addresses are wave-uniform -> s_load +
// v_fmac with SGPR operand. Block = 256 thr = 4 waves; wave covers 32 n.
// grid = (N/128, S). K/S must be a multiple of 64.
// ---------------------------------------------------------------------------
__global__ __launch_bounds__(256) void gemm_tn(
    const float* __restrict__ A0T, const float* __restrict__ A1T, int KA0,
    const float* __restrict__ W0, int ldw0,
    const float* __restrict__ W1, int ldw1, int KW0,
    float* __restrict__ P, int N, int K, int S)
{
    const int lane = threadIdx.x & 63;
    const int wid  = __builtin_amdgcn_readfirstlane(threadIdx.x >> 6);
    const int n0   = blockIdx.x * 128 + wid * 32;
    const int kc   = K / S;
    const int kbeg = blockIdx.y * kc;
    const int kend = kbeg + kc;

    float acc[32];
    #pragma unroll
    for (int j = 0; j < 32; ++j) acc[j] = 0.f;

    float aA[32], aB[32];

    auto loadA = [&](float* areg, int kpos) {
        const float* at = (kpos < KA0) ? (A0T + (size_t)kpos * 64)
                                       : (A1T + (size_t)(kpos - KA0) * 64);
        #pragma unroll
        for (int kk = 0; kk < 32; ++kk) areg[kk] = at[(kk << 6) + lane];
    };

    auto fmab = [&](const float* areg, int kpos) {
        const float* wb; int ld, kw;
        if (kpos < KW0) { wb = W0; ld = ldw0; kw = kpos; }
        else            { wb = W1; ld = ldw1; kw = kpos - KW0; }
        #pragma unroll
        for (int jg = 0; jg < 8; ++jg) {
            const float* wr0 = wb + (size_t)(n0 + jg * 4 + 0) * ld + kw;
            const float* wr1 = wr0 + ld;
            const float* wr2 = wr1 + ld;
            const float* wr3 = wr2 + ld;
            #pragma unroll
            for (int kh = 0; kh < 2; ++kh) {
                #pragma unroll
                for (int kk = 0; kk < 16; ++kk) {
                    const int k2 = kh * 16 + kk;
                    acc[jg * 4 + 0] += areg[k2] * wr0[k2];
                    acc[jg * 4 + 1] += areg[k2] * wr1[k2];
                    acc[jg * 4 + 2] += areg[k2] * wr2[k2];
                    acc[jg * 4 + 3] += areg[k2] * wr3[k2];
                }
            }
        }
    };

    loadA(aA, kbeg);
    for (int k0 = kbeg; k0 < kend; k0 += 64) {
        if (k0 + 32 < kend) loadA(aB, k0 + 32);
        fmab(aA, k0);
        if (k0 + 64 < kend) loadA(aA, k0 + 64);
        if (k0 + 32 < kend) fmab(aB, k0 + 32);
    }

    float* dst = P + ((size_t)(blockIdx.y * 64) + lane) * N + n0;
    #pragma unroll
    for (int j = 0; j < 32; j += 4)
        *(float4*)(dst + j) = make_float4(acc[j], acc[j + 1], acc[j + 2], acc[j + 3]);
}

// ---------------------------------------------------------------------------
// Softmax over M=512 (summing split-K partials + bias), write normalized attn
// to d_out, then appliedT[h][b] = sum_m aw[m] * enc[b,m,h] for this block's
// h-slice. grid = (64 b, 4 h-chunks), 256 threads.
// ---------------------------------------------------------------------------
__global__ __launch_bounds__(256) void softmax_einsum(
    const float* __restrict__ zp,    // [S][64][512] partials
    const float* __restrict__ ba,    // [512]
    const float* __restrict__ enc,   // [64][512][1024]
    float* __restrict__ appliedT,    // [1024][64]
    float* __restrict__ attn_out,    // d_out + ATT0 + step*512; index b*L*M + m
    int nsplit)
{
    __shared__ float aw[512];
    __shared__ float red[4];
    const int b  = blockIdx.x;
    const int hc = blockIdx.y;
    const int t  = threadIdx.x;

    float z0 = ba[t], z1 = ba[t + 256];
    for (int s = 0; s < nsplit; ++s) {
        const float* zr = zp + ((size_t)(s * 64 + b) << 9);
        z0 += zr[t];
        z1 += zr[t + 256];
    }
    float mx = fmaxf(z0, z1);
    #pragma unroll
    for (int off = 32; off >= 1; off >>= 1) mx = fmaxf(mx, __shfl_xor(mx, off));
    if ((t & 63) == 0) red[t >> 6] = mx;
    __syncthreads();
    mx = fmaxf(fmaxf(red[0], red[1]), fmaxf(red[2], red[3]));

    float e0 = expf(z0 - mx), e1 = expf(z1 - mx);
    aw[t] = e0; aw[t + 256] = e1;
    float ss = e0 + e1;
    #pragma unroll
    for (int off = 32; off >= 1; off >>= 1) ss += __shfl_xor(ss, off);
    __syncthreads();                 // red reads done; aw writes done
    if ((t & 63) == 0) red[t >> 6] = ss;
    __syncthreads();
    const float rinv = 1.0f / (red[0] + red[1] + red[2] + red[3]);

    if (hc == 0) {
        attn_out[(size_t)b * (LL * MM) + t]       = e0 * rinv;
        attn_out[(size_t)b * (LL * MM) + t + 256] = e1 * rinv;
    }

    // phase 2: weighted sum over encode_outputs
    const int h = (hc << 8) + t;
    const float* eb = enc + ((size_t)b << 19) + h;
    float acc = 0.f;
    #pragma unroll 8
    for (int mm = 0; mm < 512; ++mm) acc += aw[mm] * eb[(size_t)mm << 10];
    appliedT[(h << 6) + b] = acc * rinv;
}

// ---------------------------------------------------------------------------
// combT[n][b] = relu(sum_s P[s][b][n] + bias[n]); n-major threads so the
// transposed write is coalesced. 65536 threads.
// ---------------------------------------------------------------------------
__global__ __launch_bounds__(256) void reduce_act_T(
    const float* __restrict__ P, int nsplit, const float* __restrict__ bias,
    float* __restrict__ dstT)
{
    const int idx = blockIdx.x * 256 + threadIdx.x;
    const int n = idx >> 6, b = idx & 63;
    float v = bias[n];
    for (int s = 0; s < nsplit; ++s) v += P[((size_t)(s * 64 + b) << 10) + n];
    dstT[idx] = fmaxf(v, 0.f);
}

// ---------------------------------------------------------------------------
// out = relu(...): writes outT (coalesced) + the d_out decode slot (strided).
// ---------------------------------------------------------------------------
__global__ __launch_bounds__(256) void reduce_out(
    const float* __restrict__ P, int nsplit, const float* __restrict__ bias,
    float* __restrict__ outT, float* __restrict__ dout /* d_out + step*HH */)
{
    const int idx = blockIdx.x * 256 + threadIdx.x;
    const int n = idx >> 6, b = idx & 63;
    float v = bias[n];
    for (int s = 0; s < nsplit; ++s) v += P[((size_t)(s * 64 + b) << 10) + n];
    v = fmaxf(v, 0.f);
    outT[idx] = v;
    dout[(size_t)b * LH + n] = v;
}

// ---------------------------------------------------------------------------
// LSTM pointwise from gate partials gp[s][b][4096] (+ summed bias), T-layout
// state: cprevT/cT/hT are [1024][64]. n-major threads -> coalesced T I/O.
// ---------------------------------------------------------------------------
__global__ __launch_bounds__(256) void reduce_lstm_T(
    const float* __restrict__ gp, int nsplit, const float* __restrict__ bsum,
    const float* __restrict__ cprevT, float* __restrict__ hT, float* __restrict__ cT)
{
    const int idx = blockIdx.x * 256 + threadIdx.x;
    const int j = idx >> 6, b = idx & 63;
    float gi = bsum[j], gf = bsum[1024 + j], gg = bsum[2048 + j], go = bsum[3072 + j];
    for (int s = 0; s < nsplit; ++s) {
        const float* g = gp + ((size_t)(s * 64 + b) << 12);
        gi += g[j]; gf += g[1024 + j]; gg += g[2048 + j]; go += g[3072 + j];
    }
    const float c  = cprevT[idx];
    const float cn = sigmoidf_(gf) * c + sigmoidf_(gi) * tanhf(gg);
    cT[idx] = cn;
    hT[idx] = sigmoidf_(go) * tanhf(cn);
}

// ---------------------------------------------------------------------------
// Precompute kernels (run once per launch)
// ---------------------------------------------------------------------------
__global__ void add_vec(const float* __restrict__ a, const float* __restrict__ b,
                        float* __restrict__ o, int n)
{
    for (int i = blockIdx.x * blockDim.x + threadIdx.x; i < n; i += blockDim.x * gridDim.x)
        o[i] = a[i] + b[i];
}

// dstT[k*64 + b] = src[b*stride + k], k in [0,K)
__global__ void transpose64(const float* __restrict__ src, int stride,
                            float* __restrict__ dstT, int K)
{
    const int idx = blockIdx.x * blockDim.x + threadIdx.x;
    if (idx < K * 64) {
        const int k = idx >> 6, b = idx & 63;
        dstT[idx] = src[(size_t)b * stride + k];
    }
}

// ---------------------------------------------------------------------------
extern "C" void kernel_launch(void* const* d_in, const int* in_sizes, int n_in,
                              void* d_out, int out_size, void* d_ws, size_t ws_size,
                              hipStream_t stream)
{
    (void)in_sizes; (void)n_in; (void)out_size; (void)ws_size;

    const float* decode_input = (const float*)d_in[0];
    const float* h0   = (const float*)d_in[1];
    const float* c0   = (const float*)d_in[2];
    const float* enc  = (const float*)d_in[3];
    const float* Wa   = (const float*)d_in[4];
    const float* ba   = (const float*)d_in[5];
    const float* Wc   = (const float*)d_in[6];
    const float* bc   = (const float*)d_in[7];
    const float* Wo   = (const float*)d_in[8];
    const float* bo   = (const float*)d_in[9];
    const float* W1ih = (const float*)d_in[10];
    const float* W1hh = (const float*)d_in[11];
    const float* b1ih = (const float*)d_in[12];
    const float* b1hh = (const float*)d_in[13];
    const float* W2ih = (const float*)d_in[14];
    const float* W2hh = (const float*)d_in[15];
    const float* b2ih = (const float*)d_in[16];
    const float* b2hh = (const float*)d_in[17];
    const float* W3ih = (const float*)d_in[18];
    const float* W3hh = (const float*)d_in[19];
    const float* b3ih = (const float*)d_in[20];
    const float* b3hh = (const float*)d_in[21];

    float* out = (float*)d_out;
    float* ws  = (float*)d_ws;

    // workspace layout (floats) — ~45 MB total
    float* w2s   = ws;                 // 4096*1024
    float* w3s   = w2s + 4194304;      // 4096*1024
    float* b1s   = w3s + 4194304;      // 4096
    float* b2s   = b1s + 4096;
    float* b3s   = b2s + 4096;
    float* part  = b3s + 4096;         // 2097152 (max: 8*64*4096; reused by all GEMMs)
    float* dinT  = part + 2097152;     // 65536 each below
    float* h0T   = dinT + 65536;
    float* c0T   = h0T + 65536;
    float* appliedT = c0T + 65536;
    float* combT = appliedT + 65536;
    float* outT  = combT + 65536;
    float* h1T   = outT + 65536;
    float* h2T   = h1T + 65536;
    float* h3T   = h2T + 65536;
    float* c1T   = h3T + 65536;
    float* c2T   = c1T + 65536;
    float* c3T   = c2T + 65536;

    // ---- precompute: summed LSTM2/3 weights+biases, transposed initial state
    add_vec<<<2048, 256, 0, stream>>>(W2ih, W2hh, w2s, 4096 * 1024);
    add_vec<<<2048, 256, 0, stream>>>(W3ih, W3hh, w3s, 4096 * 1024);
    add_vec<<<16, 256, 0, stream>>>(b1ih, b1hh, b1s, 4096);
    add_vec<<<16, 256, 0, stream>>>(b2ih, b2hh, b2s, 4096);
    add_vec<<<16, 256, 0, stream>>>(b3ih, b3hh, b3s, 4096);
    transpose64<<<256, 256, 0, stream>>>(decode_input, LH, dinT, 1024);
    transpose64<<<256, 256, 0, stream>>>(h0, 1024, h0T, 1024);
    transpose64<<<256, 256, 0, stream>>>(c0, 1024, c0T, 1024);

    for (int step = 0; step < LL; ++step) {
        const float* inpT   = (step == 0) ? dinT : outT;
        const float* hprevT = (step == 0) ? h0T : h3T;
        const float* cprevT = (step == 0) ? c0T : c3T;

        // attention logits: z = [inp | hprev] @ Wa.T   (N=512, K=2048, S=16)
        gemm_tn<<<dim3(4, 16), 256, 0, stream>>>(inpT, hprevT, 1024,
                                                 Wa, 2048, Wa, 2048, 2048,
                                                 part, 512, 2048, 16);
        softmax_einsum<<<dim3(64, 4), 256, 0, stream>>>(
            part, ba, enc, appliedT, out + ATT0 + (size_t)step * MM, 16);

        // comb = relu([inp | applied] @ Wc.T + bc)   (N=1024, K=2048, S=16)
        gemm_tn<<<dim3(8, 16), 256, 0, stream>>>(inpT, appliedT, 1024,
                                                 Wc, 2048, Wc, 2048, 2048,
                                                 part, 1024, 2048, 16);
        reduce_act_T<<<256, 256, 0, stream>>>(part, 16, bc, combT);

        // LSTM1: gates = [comb | hprev] @ [W1ih | W1hh].T  (N=4096, K=2048, S=8)
        gemm_tn<<<dim3(32, 8), 256, 0, stream>>>(combT, hprevT, 1024,
                                                 W1ih, 1024, W1hh, 1024, 1024,
                                                 part, 4096, 2048, 8);
        reduce_lstm_T<<<256, 256, 0, stream>>>(part, 8, b1s, cprevT, h1T, c1T);

        // LSTM2: gates = h1 @ (W2ih+W2hh).T   (N=4096, K=1024, S=8)
        gemm_tn<<<dim3(32, 8), 256, 0, stream>>>(h1T, h1T, 1024,
                                                 w2s, 1024, w2s, 1024, 1024,
                                                 part, 4096, 1024, 8);
        reduce_lstm_T<<<256, 256, 0, stream>>>(part, 8, b2s, c1T, h2T, c2T);

        // LSTM3
        gemm_tn<<<dim3(32, 8), 256, 0, stream>>>(h2T, h2T, 1024,
                                                 w3s, 1024, w3s, 1024, 1024,
                                                 part, 4096, 1024, 8);
        reduce_lstm_T<<<256, 256, 0, stream>>>(part, 8, b3s, c2T, h3T, c3T);

        // out = relu(h3 @ Wo.T + bo)  (N=1024, K=1024, S=8)
        gemm_tn<<<dim3(8, 8), 256, 0, stream>>>(h3T, h3T, 1024,
                                                Wo, 1024, Wo, 1024, 1024,
                                                part, 1024, 1024, 8);
        reduce_out<<<256, 256, 0, stream>>>(part, 8, bo, outT,
                                            out + (size_t)step * HH);
    }
}

// Round 5
// 14017.717 us; speedup vs baseline: 4.8131x; 4.8131x over previous
//
#include <hip/hip_runtime.h>
#include <cmath>

// Problem constants
#define BB 64
#define LL 96
#define HH 1024
#define MM 512
#define LH 98304            // L*H
#define ATT0 6291456        // B*L*H (start of attn outputs in d_out)

typedef unsigned short u16;
typedef __attribute__((ext_vector_type(8))) short bf16x8;
typedef __attribute__((ext_vector_type(4))) float f32x4;

__device__ __forceinline__ float sigmoidf_(float x) { return 1.0f / (1.0f + expf(-x)); }

__device__ __forceinline__ u16 f2bf(float f) {           // round-to-nearest-even bf16
    union { float f; unsigned u; } v; v.f = f;
    unsigned r = v.u + 0x7fffu + ((v.u >> 16) & 1u);
    return (u16)(r >> 16);
}
__device__ __forceinline__ float bf2f(u16 h) {
    union { unsigned u; float f; } v; v.u = ((unsigned)h) << 16;
    return v.f;
}
__device__ __forceinline__ void split_bf(float v, u16& hi, u16& lo) {
    hi = f2bf(v);
    lo = f2bf(v - bf2f(hi));
}

// ---------------------------------------------------------------------------
// MFMA split-K GEMM, bf16x3 error-compensated (fp32-equivalent accuracy).
//   P[s][b][n] = sum_{k in split s} A(b,k) * W(n,k)
// A: packed planes [K/8][64][8] bf16 (hi,lo), virtual concat A0 (k<KA0) | A1.
// W: packed planes [K/8][N][8] bf16 (hi,lo) built from row-major W[N][K].
// 3 passes: Ahi*Whi + Ahi*Wlo + Alo*Whi  (alo*wlo ~2^-18, dropped).
// Block: 256 thr = 4 waves; wave w = rows 16w..16w+15; block covers 64 cols.
// grid = (N/64, S); K/S must be multiple of 32 and not cross KA0 unaligned.
// ---------------------------------------------------------------------------
__global__ __launch_bounds__(256) void gemm_mfma(
    const u16* __restrict__ A0hi, const u16* __restrict__ A0lo,
    const u16* __restrict__ A1hi, const u16* __restrict__ A1lo, int KA0,
    const u16* __restrict__ Whi, const u16* __restrict__ Wlo,
    int N, int K, float* __restrict__ P)
{
    const int lane = threadIdx.x & 63;
    const int wv   = threadIdx.x >> 6;       // m-tile index (0..3)
    const int n0   = blockIdx.x * 64;
    const int kc   = K / gridDim.y;
    const int kbeg = blockIdx.y * kc;
    const int kend = kbeg + kc;

    const int col  = lane & 15;              // n within fragment / row within A
    const int ks   = lane >> 4;              // k-subgroup (0..3)
    const int row  = (wv << 4) + col;        // global A row for this lane

    f32x4 acc[4];
    #pragma unroll
    for (int i = 0; i < 4; ++i) acc[i] = (f32x4){0.f, 0.f, 0.f, 0.f};

    #pragma unroll
    for (int seg = 0; seg < 3; ++seg) {
        const u16* Ap0 = (seg == 2) ? A0lo : A0hi;
        const u16* Ap1 = (seg == 2) ? A1lo : A1hi;
        const u16* Wp  = (seg == 1) ? Wlo  : Whi;
        for (int kb = kbeg; kb < kend; kb += 32) {
            const u16* Apl; int ka;
            if (kb < KA0) { Apl = Ap0; ka = kb; }
            else          { Apl = Ap1; ka = kb - KA0; }
            // A fragment: element (lane, j) = A[row][ka + ks*8 + j]
            bf16x8 af = *(const bf16x8*)(Apl + ((size_t)(((ka >> 3) + ks) * 64 + row) << 3));
            // B fragments: element (lane, j) = W[n0+nf*16+col][kb + ks*8 + j]
            const u16* wb = Wp + (((size_t)((kb >> 3) + ks) * N + n0 + col) << 3);
            bf16x8 bf0 = *(const bf16x8*)(wb);
            bf16x8 bf1 = *(const bf16x8*)(wb + (16 << 3));
            bf16x8 bf2 = *(const bf16x8*)(wb + (32 << 3));
            bf16x8 bf3 = *(const bf16x8*)(wb + (48 << 3));
            acc[0] = __builtin_amdgcn_mfma_f32_16x16x32_bf16(af, bf0, acc[0], 0, 0, 0);
            acc[1] = __builtin_amdgcn_mfma_f32_16x16x32_bf16(af, bf1, acc[1], 0, 0, 0);
            acc[2] = __builtin_amdgcn_mfma_f32_16x16x32_bf16(af, bf2, acc[2], 0, 0, 0);
            acc[3] = __builtin_amdgcn_mfma_f32_16x16x32_bf16(af, bf3, acc[3], 0, 0, 0);
        }
    }

    // D layout: col = lane&15, row_in_tile = ks*4 + r
    float* dst = P + ((size_t)blockIdx.y * 64 + (wv << 4) + (ks << 2)) * N + n0 + col;
    #pragma unroll
    for (int nf = 0; nf < 4; ++nf)
        #pragma unroll
        for (int r = 0; r < 4; ++r)
            dst[(size_t)r * N + nf * 16] = acc[nf][r];
}

// ---------------------------------------------------------------------------
// Softmax over M=512 (sum split-K partials + bias), write normalized attn to
// d_out, then applied[b,h] for this h-slice -> packed bf16 hi/lo planes.
// grid = (64 b, 4 h-chunks), 256 threads.
// ---------------------------------------------------------------------------
__global__ __launch_bounds__(256) void softmax_einsum(
    const float* __restrict__ zp,    // [S][64][512] partials
    const float* __restrict__ ba,    // [512]
    const float* __restrict__ enc,   // [64][512][1024]
    u16* __restrict__ apHi, u16* __restrict__ apLo,   // packed [128][64][8]
    float* __restrict__ attn_out,    // d_out + ATT0 + step*512
    int nsplit)
{
    __shared__ float aw[512];
    __shared__ float red[4];
    const int b  = blockIdx.x;
    const int hc = blockIdx.y;
    const int t  = threadIdx.x;

    float z0 = ba[t], z1 = ba[t + 256];
    for (int s = 0; s < nsplit; ++s) {
        const float* zr = zp + ((size_t)(s * 64 + b) << 9);
        z0 += zr[t];
        z1 += zr[t + 256];
    }
    float mx = fmaxf(z0, z1);
    #pragma unroll
    for (int off = 32; off >= 1; off >>= 1) mx = fmaxf(mx, __shfl_xor(mx, off));
    if ((t & 63) == 0) red[t >> 6] = mx;
    __syncthreads();
    mx = fmaxf(fmaxf(red[0], red[1]), fmaxf(red[2], red[3]));

    float e0 = expf(z0 - mx), e1 = expf(z1 - mx);
    aw[t] = e0; aw[t + 256] = e1;
    float ss = e0 + e1;
    #pragma unroll
    for (int off = 32; off >= 1; off >>= 1) ss += __shfl_xor(ss, off);
    __syncthreads();
    if ((t & 63) == 0) red[t >> 6] = ss;
    __syncthreads();
    const float rinv = 1.0f / (red[0] + red[1] + red[2] + red[3]);

    if (hc == 0) {
        attn_out[(size_t)b * (LL * MM) + t]       = e0 * rinv;
        attn_out[(size_t)b * (LL * MM) + t + 256] = e1 * rinv;
    }

    const int h = (hc << 8) + t;
    const float* eb = enc + ((size_t)b << 19) + h;
    float acc = 0.f;
    #pragma unroll 8
    for (int mm = 0; mm < 512; ++mm) acc += aw[mm] * eb[(size_t)mm << 10];
    acc *= rinv;

    u16 hi, lo; split_bf(acc, hi, lo);
    const size_t o = ((size_t)(h >> 3) << 9) + ((size_t)b << 3) + (h & 7);
    apHi[o] = hi; apLo[o] = lo;
}

// ---------------------------------------------------------------------------
// dst = relu(sum_s P + bias) -> packed bf16 planes. n-major threads.
// ---------------------------------------------------------------------------
__global__ __launch_bounds__(256) void reduce_act(
    const float* __restrict__ P, int nsplit, const float* __restrict__ bias,
    u16* __restrict__ dHi, u16* __restrict__ dLo)
{
    const int idx = blockIdx.x * 256 + threadIdx.x;
    const int n = idx >> 6, b = idx & 63;
    float v = bias[n];
    for (int s = 0; s < nsplit; ++s) v += P[((size_t)(s * 64 + b) << 10) + n];
    v = fmaxf(v, 0.f);
    u16 hi, lo; split_bf(v, hi, lo);
    const size_t o = ((size_t)(n >> 3) << 9) + ((size_t)b << 3) + (n & 7);
    dHi[o] = hi; dLo[o] = lo;
}

// out = relu(...): packed planes + fp32 d_out decode slot.
__global__ __launch_bounds__(256) void reduce_out(
    const float* __restrict__ P, int nsplit, const float* __restrict__ bias,
    u16* __restrict__ dHi, u16* __restrict__ dLo, float* __restrict__ dout)
{
    const int idx = blockIdx.x * 256 + threadIdx.x;
    const int n = idx >> 6, b = idx & 63;
    float v = bias[n];
    for (int s = 0; s < nsplit; ++s) v += P[((size_t)(s * 64 + b) << 10) + n];
    v = fmaxf(v, 0.f);
    u16 hi, lo; split_bf(v, hi, lo);
    const size_t o = ((size_t)(n >> 3) << 9) + ((size_t)b << 3) + (n & 7);
    dHi[o] = hi; dLo[o] = lo;
    dout[(size_t)b * LH + n] = v;
}

// ---------------------------------------------------------------------------
// LSTM pointwise: gate partials gp[s][b][4096] + summed bias; cprevT fp32
// [1024][64]; outputs cT fp32 + h as packed bf16 planes.
// ---------------------------------------------------------------------------
__global__ __launch_bounds__(256) void reduce_lstm(
    const float* __restrict__ gp, int nsplit, const float* __restrict__ bsum,
    const float* __restrict__ cprevT, float* __restrict__ cT,
    u16* __restrict__ hHi, u16* __restrict__ hLo)
{
    const int idx = blockIdx.x * 256 + threadIdx.x;
    const int j = idx >> 6, b = idx & 63;
    float gi = bsum[j], gf = bsum[1024 + j], gg = bsum[2048 + j], go = bsum[3072 + j];
    for (int s = 0; s < nsplit; ++s) {
        const float* g = gp + ((size_t)(s * 64 + b) << 12);
        gi += g[j]; gf += g[1024 + j]; gg += g[2048 + j]; go += g[3072 + j];
    }
    const float c  = cprevT[idx];
    const float cn = sigmoidf_(gf) * c + sigmoidf_(gi) * tanhf(gg);
    cT[idx] = cn;
    const float hv = sigmoidf_(go) * tanhf(cn);
    u16 hi, lo; split_bf(hv, hi, lo);
    const size_t o = ((size_t)(j >> 3) << 9) + ((size_t)b << 3) + (j & 7);
    hHi[o] = hi; hLo[o] = lo;
}

// ---------------------------------------------------------------------------
// Precompute kernels
// ---------------------------------------------------------------------------
// Build packed weight planes [K/8][N][8] (hi,lo) from fp32 sources.
// addmode: w = src0[n*K+k] + src1[n*K+k]. else concat: k<K0 -> src0 (ld=K0),
// k>=K0 -> src1 (ld=K-K0). Single matrix: K0=K. Threads = N*K/8.
__global__ void pack_w(const float* __restrict__ src0, const float* __restrict__ src1,
                       int K0, int addmode, int N, int K,
                       u16* __restrict__ hi8, u16* __restrict__ lo8)
{
    const int tid = blockIdx.x * 256 + threadIdx.x;
    const int kg = tid / N, n = tid % N;
    #pragma unroll
    for (int j = 0; j < 8; ++j) {
        const int k = (kg << 3) + j;
        float w;
        if (addmode)      w = src0[(size_t)n * K + k] + src1[(size_t)n * K + k];
        else if (k < K0)  w = src0[(size_t)n * K0 + k];
        else              w = src1[(size_t)n * (K - K0) + (k - K0)];
        u16 h, l; split_bf(w, h, l);
        hi8[((size_t)tid << 3) + j] = h;
        lo8[((size_t)tid << 3) + j] = l;
    }
}

// Pack a [64][1024] fp32 activation (row stride `rowstride`) into planes.
__global__ void pack_act(const float* __restrict__ src, int rowstride,
                         u16* __restrict__ hi8, u16* __restrict__ lo8)
{
    const int idx = blockIdx.x * 256 + threadIdx.x;   // 65536 threads
    const int j = idx & 7, b = (idx >> 3) & 63, kg = idx >> 9;
    const float v = src[(size_t)b * rowstride + (kg << 3) + j];
    u16 h, l; split_bf(v, h, l);
    hi8[idx] = h; lo8[idx] = l;
}

__global__ void add_vec(const float* __restrict__ a, const float* __restrict__ b,
                        float* __restrict__ o, int n)
{
    for (int i = blockIdx.x * blockDim.x + threadIdx.x; i < n; i += blockDim.x * gridDim.x)
        o[i] = a[i] + b[i];
}

// dstT[k*64+b] = src[b*stride + k]
__global__ void transpose64(const float* __restrict__ src, int stride,
                            float* __restrict__ dstT, int K)
{
    const int idx = blockIdx.x * blockDim.x + threadIdx.x;
    if (idx < K * 64) {
        const int k = idx >> 6, b = idx & 63;
        dstT[idx] = src[(size_t)b * stride + k];
    }
}

// ---------------------------------------------------------------------------
extern "C" void kernel_launch(void* const* d_in, const int* in_sizes, int n_in,
                              void* d_out, int out_size, void* d_ws, size_t ws_size,
                              hipStream_t stream)
{
    (void)in_sizes; (void)n_in; (void)out_size; (void)ws_size;

    const float* decode_input = (const float*)d_in[0];
    const float* h0   = (const float*)d_in[1];
    const float* c0   = (const float*)d_in[2];
    const float* enc  = (const float*)d_in[3];
    const float* Wa   = (const float*)d_in[4];
    const float* ba   = (const float*)d_in[5];
    const float* Wc   = (const float*)d_in[6];
    const float* bc   = (const float*)d_in[7];
    const float* Wo   = (const float*)d_in[8];
    const float* bo   = (const float*)d_in[9];
    const float* W1ih = (const float*)d_in[10];
    const float* W1hh = (const float*)d_in[11];
    const float* b1ih = (const float*)d_in[12];
    const float* b1hh = (const float*)d_in[13];
    const float* W2ih = (const float*)d_in[14];
    const float* W2hh = (const float*)d_in[15];
    const float* b2ih = (const float*)d_in[16];
    const float* b2hh = (const float*)d_in[17];
    const float* W3ih = (const float*)d_in[18];
    const float* W3hh = (const float*)d_in[19];
    const float* b3ih = (const float*)d_in[20];
    const float* b3hh = (const float*)d_in[21];

    float* out = (float*)d_out;
    float* ws  = (float*)d_ws;

    // ---- workspace layout (~91 MB) ----
    float* part = ws;                    // 2,097,152 floats (8 MB; max split-K partials)
    float* c0T  = part + 2097152;        // 65536 each
    float* c1T  = c0T + 65536;
    float* c2T  = c1T + 65536;
    float* c3T  = c2T + 65536;
    float* b1s  = c3T + 65536;           // 4096 each
    float* b2s  = b1s + 4096;
    float* b3s  = b2s + 4096;
    u16* up = (u16*)(b3s + 4096);
    // weight planes [K/8][N][8]
    u16* waH = up;             u16* waL = waH + 1048576;   // 512x2048
    u16* wcH = waL + 1048576;  u16* wcL = wcH + 2097152;   // 1024x2048
    u16* w1H = wcL + 2097152;  u16* w1L = w1H + 8388608;   // 4096x2048
    u16* w2H = w1L + 8388608;  u16* w2L = w2H + 4194304;   // 4096x1024 (summed)
    u16* w3H = w2L + 4194304;  u16* w3L = w3H + 4194304;
    u16* woH = w3L + 4194304;  u16* woL = woH + 1048576;   // 1024x1024
    // activation planes [128][64][8] (65536 u16 each)
    u16* dinH = woL + 1048576; u16* dinL = dinH + 65536;
    u16* h0H  = dinL + 65536;  u16* h0L  = h0H + 65536;
    u16* outH = h0L + 65536;   u16* outL = outH + 65536;
    u16* apH  = outL + 65536;  u16* apL  = apH + 65536;    // applied
    u16* cbH  = apL + 65536;   u16* cbL  = cbH + 65536;    // comb
    u16* h1H  = cbL + 65536;   u16* h1L  = h1H + 65536;
    u16* h2H  = h1L + 65536;   u16* h2L  = h2H + 65536;
    u16* h3H  = h2L + 65536;   u16* h3L  = h3H + 65536;

    // ---- precompute: packed weights, summed biases, initial state ----
    pack_w<<<512, 256, 0, stream>>>(Wa, Wa, 2048, 0, 512, 2048, waH, waL);
    pack_w<<<1024, 256, 0, stream>>>(Wc, Wc, 2048, 0, 1024, 2048, wcH, wcL);
    pack_w<<<4096, 256, 0, stream>>>(W1ih, W1hh, 1024, 0, 4096, 2048, w1H, w1L);
    pack_w<<<2048, 256, 0, stream>>>(W2ih, W2hh, 1024, 1, 4096, 1024, w2H, w2L);
    pack_w<<<2048, 256, 0, stream>>>(W3ih, W3hh, 1024, 1, 4096, 1024, w3H, w3L);
    pack_w<<<512, 256, 0, stream>>>(Wo, Wo, 1024, 0, 1024, 1024, woH, woL);
    add_vec<<<16, 256, 0, stream>>>(b1ih, b1hh, b1s, 4096);
    add_vec<<<16, 256, 0, stream>>>(b2ih, b2hh, b2s, 4096);
    add_vec<<<16, 256, 0, stream>>>(b3ih, b3hh, b3s, 4096);
    pack_act<<<256, 256, 0, stream>>>(decode_input, LH, dinH, dinL);
    pack_act<<<256, 256, 0, stream>>>(h0, 1024, h0H, h0L);
    transpose64<<<256, 256, 0, stream>>>(c0, 1024, c0T, 1024);

    for (int step = 0; step < LL; ++step) {
        const u16* inH = (step == 0) ? dinH : outH;
        const u16* inL = (step == 0) ? dinL : outL;
        const u16* hpH = (step == 0) ? h0H : h3H;
        const u16* hpL = (step == 0) ? h0L : h3L;
        const float* cprevT = (step == 0) ? c0T : c3T;

        // attention logits: z = [inp | hprev] @ Wa.T  (N=512, K=2048, S=16)
        gemm_mfma<<<dim3(8, 16), 256, 0, stream>>>(inH, inL, hpH, hpL, 1024,
                                                   waH, waL, 512, 2048, part);
        softmax_einsum<<<dim3(64, 4), 256, 0, stream>>>(
            part, ba, enc, apH, apL, out + ATT0 + (size_t)step * MM, 16);

        // comb = relu([inp | applied] @ Wc.T + bc)  (N=1024, K=2048, S=16)
        gemm_mfma<<<dim3(16, 16), 256, 0, stream>>>(inH, inL, apH, apL, 1024,
                                                    wcH, wcL, 1024, 2048, part);
        reduce_act<<<256, 256, 0, stream>>>(part, 16, bc, cbH, cbL);

        // LSTM1: gates = [comb | hprev] @ [W1ih|W1hh].T  (N=4096, K=2048, S=8)
        gemm_mfma<<<dim3(64, 8), 256, 0, stream>>>(cbH, cbL, hpH, hpL, 1024,
                                                   w1H, w1L, 4096, 2048, part);
        reduce_lstm<<<256, 256, 0, stream>>>(part, 8, b1s, cprevT, c1T, h1H, h1L);

        // LSTM2: gates = h1 @ (W2ih+W2hh).T  (N=4096, K=1024, S=8)
        gemm_mfma<<<dim3(64, 8), 256, 0, stream>>>(h1H, h1L, h1H, h1L, 1024,
                                                   w2H, w2L, 4096, 1024, part);
        reduce_lstm<<<256, 256, 0, stream>>>(part, 8, b2s, c1T, c2T, h2H, h2L);

        // LSTM3
        gemm_mfma<<<dim3(64, 8), 256, 0, stream>>>(h2H, h2L, h2H, h2L, 1024,
                                                   w3H, w3L, 4096, 1024, part);
        reduce_lstm<<<256, 256, 0, stream>>>(part, 8, b3s, c2T, c3T, h3H, h3L);

        // out = relu(h3 @ Wo.T + bo)  (N=1024, K=1024, S=8)
        gemm_mfma<<<dim3(16, 8), 256, 0, stream>>>(h3H, h3L, h3H, h3L, 1024,
                                                   woH, woL, 1024, 1024, part);
        reduce_out<<<256, 256, 0, stream>>>(part, 8, bo, outH, outL,
                                            out + (size_t)step * HH);
    }
}